// Round 11
// baseline (141.467 us; speedup 1.0000x reference)
//
#include <hip/hip_runtime.h>
#include <hip/hip_bf16.h>
#include <math.h>

typedef __bf16 bf16x8 __attribute__((ext_vector_type(8)));
typedef float  f32x4  __attribute__((ext_vector_type(4)));

#define BB 2
#define C1 256
#define C2 256
#define HH 64
#define WW 64
#define HW 4096
#define OCH 27
#define EPSV 1e-5f

// workspace layout (bytes)
#define WBF_OFF  0u          // 589824 bf16 (frag-ordered w_dcn)
#define WOFF_OFF 1179648u    // 73728 bf16 (frag-ordered w_off)
#define XT_OFF   1327104u    // 2*4096*256 bf16 = 4 MB (HWC)

// ---------------------------------------------------------------------------
// MERGED prep kernel. Block ranges:
//   [0,512):   x [b][c][hw] fp32 -> xT [b][hw][c] bf16 (LDS tile transpose)
//   [512,800): w_dcn -> frag-ordered wbfS  (K tap-major; see r9)
//   [800,836): w_off -> frag-ordered woffS (N padded 27->32)
// All three are independent -> run concurrently in one launch.
// ---------------------------------------------------------------------------
__global__ __launch_bounds__(256) void prep_kernel(
    const float* __restrict__ x, const float* __restrict__ w_dcn,
    const float* __restrict__ w_off, __bf16* __restrict__ xT,
    __bf16* __restrict__ wbfS, __bf16* __restrict__ woffS)
{
    __shared__ __bf16 tile[64][72];
    const int bi = blockIdx.x, tid = threadIdx.x;

    if (bi < 512) {
        const int b = bi >> 8;
        const int ht = (bi & 255) >> 2;
        const int ct = bi & 3;
        const int hw_l = tid & 63, cg = tid >> 6;
        const float* src = x + ((size_t)(b * 256 + ct * 64 + cg * 16) << 12)
                             + ht * 64 + hw_l;
        #pragma unroll
        for (int i = 0; i < 16; i++)
            tile[hw_l][cg * 16 + i] = (__bf16)src[(size_t)i << 12];
        __syncthreads();
        const int hw_o = tid >> 2, cq = tid & 3;
        __bf16* dst = xT + ((size_t)(b * HW + ht * 64 + hw_o) << 8)
                         + ct * 64 + cq * 16;
        *(bf16x8*)dst       = *(const bf16x8*)&tile[hw_o][cq * 16];
        *(bf16x8*)(dst + 8) = *(const bf16x8*)&tile[hw_o][cq * 16 + 8];
    } else if (bi < 800) {
        int t = (bi - 512) * 256 + tid;        // < 73728
        int l = t & 63;
        int nb = (t >> 6) & 15;
        int ks = (t >> 10) & 1;
        int kb = t >> 11;
        int o = nb * 16 + (l & 15);
        int kq = (l >> 4) & 3;
        bf16x8 v;
        #pragma unroll
        for (int j = 0; j < 8; j++) {
            int K = kb * 64 + ks * 32 + kq * 8 + j;
            v[j] = (__bf16)w_dcn[o * 2304 + (K & 255) * 9 + (K >> 8)];
        }
        *(bf16x8*)(wbfS + (size_t)t * 8) = v;
    } else {
        int t = (bi - 800) * 256 + tid;        // < 9216
        int l = t & 63;
        int nf = (t >> 6) & 1;
        int ks = (t >> 7) & 1;
        int kb = t >> 8;
        int o = nf * 16 + (l & 15);
        int kq = (l >> 4) & 3;
        bf16x8 v;
        #pragma unroll
        for (int j = 0; j < 8; j++) {
            int K = kb * 64 + ks * 32 + kq * 8 + j;
            v[j] = (o < OCH) ? (__bf16)w_off[o * 2304 + (K & 255) * 9 + (K >> 8)]
                             : (__bf16)0.f;
        }
        *(bf16x8*)(woffS + (size_t)t * 8) = v;
    }
}

// ---------------------------------------------------------------------------
// MEGA-FUSED kernel: offset conv (MFMA) + metadata + deformable gather +
// MFMA GEMM + BN + SiLU. Grid 1024 = 512 pixel-tiles (M=16) x 2 N-halves
// (N=128) -> 4 blocks/CU = 4 waves/SIMD (__launch_bounds__(256,4)).
//   Phase -1: om tile for the 16 px via 4-wave K-split MFMA (woffS), LDS
//             reduce + bias -> sOm (no global om round-trip).
//   Phase 0:  bilinear metadata from sOm.
//   Main:     barrier-free K-split; gather A direct to registers from HWC
//             xT (4 corner bf16x8 loads / 8ch); B frag-ordered, batches of 4.
//   End:      2-stage LDS K-reduction (sC stride 136 -> <=2-way banks),
//             coalesced BN+SiLU epilogue.
// ---------------------------------------------------------------------------
union SU {
    float sD[4][16][33];     // phase -1 reduction (8.4 KB)
    float sC[2][16][136];    // main K-reduction (17.4 KB)
};

__global__ __launch_bounds__(256, 4) void fused_kernel(
    const __bf16* __restrict__ xT, const __bf16* __restrict__ wbfS,
    const __bf16* __restrict__ woffS, const float* __restrict__ b_off,
    const float* __restrict__ gamma, const float* __restrict__ beta,
    const float* __restrict__ rmean, const float* __restrict__ rvar,
    float* __restrict__ out)
{
    __shared__ SU u;
    __shared__ float  sOm[32][16];       // om tile [oc][px] (2 KB)
    __shared__ int4   sO[9][16];         // corner byte offsets
    __shared__ float4 sW[9][16];         // corner weights

    const int tid = threadIdx.x, wv = tid >> 6, lane = tid & 63;
    const int bi = blockIdx.x;
    const int xcd = bi & 7, rr = bi >> 3;
    const int g = xcd * 64 + (rr >> 1);  // pixel tile [0,512), XCD-banded
    const int nHalf = rr & 1;            // N half [0,2)
    const int pixBase = g * 16;
    const int b = pixBase >> 12;
    const int hwBase = pixBase & 4095;
    const int h = hwBase >> 6, w0 = hwBase & 63;
    const int n15 = lane & 15, q4 = lane >> 4;

    const char* xb = (const char*)xT + ((size_t)b << 12) * 512;

    // ---------------- Phase -1: offset conv for this pixel tile ----------
    {
        f32x4 acc2[2];
        #pragma unroll
        for (int j = 0; j < 2; j++) acc2[j] = (f32x4){0.f, 0.f, 0.f, 0.f};

        for (int i = 0; i < 9; i++) {
            const int kb = wv * 9 + i;
            const int k = kb >> 2, cc = kb & 3;
            const int kh = k / 3, kw = k % 3;
            const int hh = h + kh - 1;
            const int ww = w0 + n15 + kw - 1;
            const bool valid = (hh >= 0) && (hh < HH) && (ww >= 0) && (ww < WW);
            const int hc = min(max(hh, 0), HH - 1);
            const int wc = min(max(ww, 0), WW - 1);
            const char* src = xb + (size_t)(hc * WW + wc) * 512
                                 + (cc * 64 + q4 * 8) * 2;
            bf16x8 af[2];
            af[0] = *(const bf16x8*)src;
            af[1] = *(const bf16x8*)(src + 64);
            if (!valid) {
                #pragma unroll
                for (int j = 0; j < 8; j++) {
                    af[0][j] = (__bf16)0.f; af[1][j] = (__bf16)0.f;
                }
            }
            #pragma unroll
            for (int nf = 0; nf < 2; nf++) {
                #pragma unroll
                for (int ks = 0; ks < 2; ks++) {
                    bf16x8 bfr = *(const bf16x8*)(woffS
                        + ((size_t)(((kb * 2 + ks) * 2 + nf) * 64 + lane)) * 8);
                    acc2[nf] = __builtin_amdgcn_mfma_f32_16x16x32_bf16(
                        af[ks], bfr, acc2[nf], 0, 0, 0);
                }
            }
        }
        #pragma unroll
        for (int nf = 0; nf < 2; nf++)
            #pragma unroll
            for (int r = 0; r < 4; r++)
                u.sD[wv][q4 * 4 + r][nf * 16 + n15] = acc2[nf][r];
    }
    __syncthreads();
    for (int t = tid; t < OCH * 16; t += 256) {
        int oc = t >> 4, p = t & 15;
        sOm[oc][p] = b_off[oc] + u.sD[0][p][oc] + u.sD[1][p][oc]
                               + u.sD[2][p][oc] + u.sD[3][p][oc];
    }
    __syncthreads();

    // ---------------- Phase 0: bilinear metadata from sOm ----------------
    if (tid < 144) {
        int k = tid >> 4, p = tid & 15;
        float dy = sOm[2 * k][p];
        float dx = sOm[2 * k + 1][p];
        float mm = sOm[18 + k][p];
        mm = 1.f / (1.f + __expf(-mm));
        float py = (float)(h - 1 + k / 3) + dy;
        float px = (float)(w0 + p - 1 + k % 3) + dx;
        float y0f = floorf(py), x0f = floorf(px);
        float ly = py - y0f, lx = px - x0f;
        int y0 = (int)y0f, x0 = (int)x0f;
        int yc0 = min(max(y0, 0), HH - 1),     yc1 = min(max(y0 + 1, 0), HH - 1);
        int xc0 = min(max(x0, 0), WW - 1),     xc1 = min(max(x0 + 1, 0), WW - 1);
        float vy0 = (y0 >= 0 && y0 < HH) ? 1.f : 0.f;
        float vy1 = (y0 + 1 >= 0 && y0 + 1 < HH) ? 1.f : 0.f;
        float vx0 = (x0 >= 0 && x0 < WW) ? 1.f : 0.f;
        float vx1 = (x0 + 1 >= 0 && x0 + 1 < WW) ? 1.f : 0.f;
        sO[k][p] = (int4){(yc0 * WW + xc0) * 512, (yc0 * WW + xc1) * 512,
                          (yc1 * WW + xc0) * 512, (yc1 * WW + xc1) * 512};
        sW[k][p] = (float4){(1.f - ly) * (1.f - lx) * vy0 * vx0 * mm,
                            (1.f - ly) * lx         * vy0 * vx1 * mm,
                            ly         * (1.f - lx) * vy1 * vx0 * mm,
                            ly         * lx         * vy1 * vx1 * mm};
    }
    __syncthreads();

    // ---------------- Main: barrier-free K-split GEMM ---------------------
    f32x4 acc[8];                        // 32 VGPRs
    #pragma unroll
    for (int j = 0; j < 8; j++) acc[j] = (f32x4){0.f, 0.f, 0.f, 0.f};

    for (int i = 0; i < 9; i++) {
        const int kb = wv * 9 + i;
        const int k = kb >> 2, cc = kb & 3;
        const int4   O = sO[k][n15];
        const float4 W = sW[k][n15];
        const char* base = xb + (cc * 64 + q4 * 8) * 2;

        bf16x8 af[2];
        #pragma unroll
        for (int ks = 0; ks < 2; ks++) {
            const char* bc = base + ks * 64;
            bf16x8 c00 = *(const bf16x8*)(bc + O.x);
            bf16x8 c01 = *(const bf16x8*)(bc + O.y);
            bf16x8 c10 = *(const bf16x8*)(bc + O.z);
            bf16x8 c11 = *(const bf16x8*)(bc + O.w);
            bf16x8 a;
            #pragma unroll
            for (int j = 0; j < 8; j++) {
                float v = W.x * (float)c00[j] + W.y * (float)c01[j]
                        + W.z * (float)c10[j] + W.w * (float)c11[j];
                a[j] = (__bf16)v;
            }
            af[ks] = a;
        }

        #pragma unroll
        for (int half = 0; half < 2; half++) {
            bf16x8 bfr[4][2];
            #pragma unroll
            for (int nb = 0; nb < 4; nb++)
                #pragma unroll
                for (int ks = 0; ks < 2; ks++)
                    bfr[nb][ks] = *(const bf16x8*)(wbfS
                        + ((size_t)(((kb * 2 + ks) * 16 + nHalf * 8 + half * 4 + nb)
                                    * 64 + lane)) * 8);
            #pragma unroll
            for (int nb = 0; nb < 4; nb++)
                #pragma unroll
                for (int ks = 0; ks < 2; ks++)
                    acc[half * 4 + nb] = __builtin_amdgcn_mfma_f32_16x16x32_bf16(
                        af[ks], bfr[nb][ks], acc[half * 4 + nb], 0, 0, 0);
        }
    }

    // ---------------- 2-stage cross-wave K-reduction ----------------------
    if (wv < 2) {
        #pragma unroll
        for (int nb = 0; nb < 8; nb++)
            #pragma unroll
            for (int r = 0; r < 4; r++)
                u.sC[wv][q4 * 4 + r][nb * 16 + n15] = acc[nb][r];
    }
    __syncthreads();
    if (wv >= 2) {
        #pragma unroll
        for (int nb = 0; nb < 8; nb++)
            #pragma unroll
            for (int r = 0; r < 4; r++)
                u.sC[wv - 2][q4 * 4 + r][nb * 16 + n15] += acc[nb][r];
    }
    __syncthreads();

    // ---------------- Epilogue: BN + SiLU ---------------------------------
    const int px = tid & 15, og = tid >> 4;
    float* ob = out + ((size_t)b * C2 << 12) + hwBase + px;
    #pragma unroll
    for (int ii = 0; ii < 8; ii++) {
        int col = og * 8 + ii;               // [0,128)
        int o = nHalf * 128 + col;
        float s = u.sC[0][px][col] + u.sC[1][px][col];
        float inv = gamma[o] * rsqrtf(rvar[o] + EPSV);
        float sh = beta[o] - rmean[o] * inv;
        float y = s * inv + sh;
        ob[(size_t)o << 12] = y * (1.f / (1.f + __expf(-y)));
    }
}

// ---------------------------------------------------------------------------
extern "C" void kernel_launch(void* const* d_in, const int* in_sizes, int n_in,
                              void* d_out, int out_size, void* d_ws, size_t ws_size,
                              hipStream_t stream) {
    const float* x      = (const float*)d_in[0];
    const float* w_off  = (const float*)d_in[1];
    const float* b_off  = (const float*)d_in[2];
    const float* w_dcn  = (const float*)d_in[3];
    const float* gamma  = (const float*)d_in[4];
    const float* beta   = (const float*)d_in[5];
    const float* rmean  = (const float*)d_in[6];
    const float* rvar   = (const float*)d_in[7];
    float* out = (float*)d_out;

    char* ws = (char*)d_ws;
    __bf16* wbfS  = (__bf16*)(ws + WBF_OFF);
    __bf16* woffS = (__bf16*)(ws + WOFF_OFF);
    __bf16* xT    = (__bf16*)(ws + XT_OFF);

    prep_kernel<<<836, 256, 0, stream>>>(x, w_dcn, w_off, xT, wbfS, woffS);
    fused_kernel<<<1024, 256, 0, stream>>>(xT, wbfS, woffS, b_off,
                                           gamma, beta, rmean, rvar, out);
}

// Round 12
// 122.253 us; speedup vs baseline: 1.1572x; 1.1572x over previous
//
#include <hip/hip_runtime.h>
#include <hip/hip_bf16.h>
#include <math.h>

typedef __bf16 bf16x8 __attribute__((ext_vector_type(8)));
typedef float  f32x4  __attribute__((ext_vector_type(4)));

#define BB 2
#define C1 256
#define C2 256
#define HH 64
#define WW 64
#define HW 4096
#define OCH 27
#define EPSV 1e-5f

// workspace layout (bytes)
#define WBF_OFF  0u          // 589824 bf16 (frag-ordered w_dcn)
#define WOFF_OFF 1179648u    // 73728 bf16 (frag-ordered w_off)
#define XT_OFF   1327104u    // 2*4096*256 bf16 = 4 MB (HWC)

// ---------------------------------------------------------------------------
// MERGED prep kernel. Block ranges:
//   [0,512):   x [b][c][hw] fp32 -> xT [b][hw][c] bf16 (LDS transpose)
//   [512,576): w_dcn -> frag-ordered wbfS, COALESCED via LDS reorder:
//              block (nb, qtr) reads 16 contiguous 2304B row-chunks as
//              float4, stages bf16 in LDS, writes frag-order contiguously.
//   [576,612): w_off -> frag-ordered woffS (tiny, scalar).
// ---------------------------------------------------------------------------
__global__ __launch_bounds__(256) void prep_kernel(
    const float* __restrict__ x, const float* __restrict__ w_dcn,
    const float* __restrict__ w_off, __bf16* __restrict__ xT,
    __bf16* __restrict__ wbfS, __bf16* __restrict__ woffS)
{
    __shared__ __bf16 tile[64][72];
    __shared__ __bf16 lw[16][584];       // 18.7 KB, stride 584 (<=2-way banks)
    const int bi = blockIdx.x, tid = threadIdx.x;

    if (bi < 512) {
        const int b = bi >> 8;
        const int ht = (bi & 255) >> 2;
        const int ct = bi & 3;
        const int hw_l = tid & 63, cg = tid >> 6;
        const float* src = x + ((size_t)(b * 256 + ct * 64 + cg * 16) << 12)
                             + ht * 64 + hw_l;
        #pragma unroll
        for (int i = 0; i < 16; i++)
            tile[hw_l][cg * 16 + i] = (__bf16)src[(size_t)i << 12];
        __syncthreads();
        const int hw_o = tid >> 2, cq = tid & 3;
        __bf16* dst = xT + ((size_t)(b * HW + ht * 64 + hw_o) << 8)
                         + ct * 64 + cq * 16;
        *(bf16x8*)dst       = *(const bf16x8*)&tile[hw_o][cq * 16];
        *(bf16x8*)(dst + 8) = *(const bf16x8*)&tile[hw_o][cq * 16 + 8];
    } else if (bi < 576) {
        const int b2 = bi - 512;
        const int nb = b2 >> 2, qtr = b2 & 3;
        // read: 16 o-rows x 576 contiguous floats (w[o][qtr*576 .. +576))
        #pragma unroll
        for (int ii = 0; ii < 9; ii++) {
            int m = tid + 256 * ii;          // float4 index, < 2304
            int base = m * 4;
            int o_l = base / 576;
            int f = base - o_l * 576;
            float4 v = *(const float4*)(w_dcn
                + (size_t)(nb * 16 + o_l) * 2304 + qtr * 576 + f);
            lw[o_l][f]     = (__bf16)v.x;
            lw[o_l][f + 1] = (__bf16)v.y;
            lw[o_l][f + 2] = (__bf16)v.z;
            lw[o_l][f + 3] = (__bf16)v.w;
        }
        __syncthreads();
        // write: frag order, contiguous (consecutive tid -> consecutive dst)
        #pragma unroll
        for (int ii = 0; ii < 36; ii++) {
            int e = ii * 256 + tid;          // < 9216
            int seg = e >> 9, s = e & 511;
            int lane = s >> 3, j = s & 7;
            int tap = seg >> 1, ks = seg & 1;
            int kb = tap * 4 + qtr;
            int o_l = lane & 15, kq = (lane >> 4) & 3;
            int c_local = ks * 32 + kq * 8 + j;
            wbfS[((size_t)(((kb * 2 + ks) * 16 + nb) * 64 + lane)) * 8 + j]
                = lw[o_l][c_local * 9 + tap];
        }
    } else {
        int t = (bi - 576) * 256 + tid;      // < 9216
        int l = t & 63;
        int nf = (t >> 6) & 1;
        int ks = (t >> 7) & 1;
        int kb = t >> 8;
        int o = nf * 16 + (l & 15);
        int kq = (l >> 4) & 3;
        bf16x8 v;
        #pragma unroll
        for (int j = 0; j < 8; j++) {
            int K = kb * 64 + ks * 32 + kq * 8 + j;
            v[j] = (o < OCH) ? (__bf16)w_off[o * 2304 + (K & 255) * 9 + (K >> 8)]
                             : (__bf16)0.f;
        }
        *(bf16x8*)(woffS + (size_t)t * 8) = v;
    }
}

// ---------------------------------------------------------------------------
// MEGA-FUSED kernel: offset conv (MFMA) + metadata + deformable gather +
// MFMA GEMM + BN + SiLU. Grid 512 (M=16, FULL N=256 per block -> no
// duplication), 2 blocks/CU, no launch-bounds VGPR cap (r11 lesson).
// Main loop is r10's known-good barrier-free K-split (9 chunks/wave,
// register gather from HWC xT, frag-ordered B in batches of 8).
// ---------------------------------------------------------------------------
union SU {
    float sD[4][16][33];     // phase -1 reduction (8.4 KB)
    float sC[2][16][260];    // main K-reduction (33.3 KB)
};

__global__ __launch_bounds__(256) void fused_kernel(
    const __bf16* __restrict__ xT, const __bf16* __restrict__ wbfS,
    const __bf16* __restrict__ woffS, const float* __restrict__ b_off,
    const float* __restrict__ gamma, const float* __restrict__ beta,
    const float* __restrict__ rmean, const float* __restrict__ rvar,
    float* __restrict__ out)
{
    __shared__ SU u;
    __shared__ float  sOm[32][16];       // om tile [oc][px]
    __shared__ int4   sO[9][16];         // corner byte offsets
    __shared__ float4 sW[9][16];         // corner weights

    const int tid = threadIdx.x, wv = tid >> 6, lane = tid & 63;
    const int g = (blockIdx.x & 7) * 64 + (blockIdx.x >> 3);   // XCD swizzle
    const int pixBase = g * 16;
    const int b = pixBase >> 12;
    const int hwBase = pixBase & 4095;
    const int h = hwBase >> 6, w0 = hwBase & 63;
    const int n15 = lane & 15, q4 = lane >> 4;

    const char* xb = (const char*)xT + ((size_t)b << 12) * 512;

    // ---------------- Phase -1: offset conv for this pixel tile ----------
    {
        f32x4 acc2[2];
        #pragma unroll
        for (int j = 0; j < 2; j++) acc2[j] = (f32x4){0.f, 0.f, 0.f, 0.f};

        for (int i = 0; i < 9; i++) {
            const int kb = wv * 9 + i;
            const int k = kb >> 2, cc = kb & 3;
            const int kh = k / 3, kw = k % 3;
            const int hh = h + kh - 1;
            const int ww = w0 + n15 + kw - 1;
            const bool valid = (hh >= 0) && (hh < HH) && (ww >= 0) && (ww < WW);
            const int hc = min(max(hh, 0), HH - 1);
            const int wc = min(max(ww, 0), WW - 1);
            const char* src = xb + (size_t)(hc * WW + wc) * 512
                                 + (cc * 64 + q4 * 8) * 2;
            bf16x8 af[2];
            af[0] = *(const bf16x8*)src;
            af[1] = *(const bf16x8*)(src + 64);
            if (!valid) {
                #pragma unroll
                for (int j = 0; j < 8; j++) {
                    af[0][j] = (__bf16)0.f; af[1][j] = (__bf16)0.f;
                }
            }
            #pragma unroll
            for (int nf = 0; nf < 2; nf++) {
                #pragma unroll
                for (int ks = 0; ks < 2; ks++) {
                    bf16x8 bfr = *(const bf16x8*)(woffS
                        + ((size_t)(((kb * 2 + ks) * 2 + nf) * 64 + lane)) * 8);
                    acc2[nf] = __builtin_amdgcn_mfma_f32_16x16x32_bf16(
                        af[ks], bfr, acc2[nf], 0, 0, 0);
                }
            }
        }
        #pragma unroll
        for (int nf = 0; nf < 2; nf++)
            #pragma unroll
            for (int r = 0; r < 4; r++)
                u.sD[wv][q4 * 4 + r][nf * 16 + n15] = acc2[nf][r];
    }
    __syncthreads();
    for (int t = tid; t < OCH * 16; t += 256) {
        int oc = t >> 4, p = t & 15;
        sOm[oc][p] = b_off[oc] + u.sD[0][p][oc] + u.sD[1][p][oc]
                               + u.sD[2][p][oc] + u.sD[3][p][oc];
    }
    __syncthreads();

    // ---------------- Phase 0: bilinear metadata from sOm ----------------
    if (tid < 144) {
        int k = tid >> 4, p = tid & 15;
        float dy = sOm[2 * k][p];
        float dx = sOm[2 * k + 1][p];
        float mm = sOm[18 + k][p];
        mm = 1.f / (1.f + __expf(-mm));
        float py = (float)(h - 1 + k / 3) + dy;
        float px = (float)(w0 + p - 1 + k % 3) + dx;
        float y0f = floorf(py), x0f = floorf(px);
        float ly = py - y0f, lx = px - x0f;
        int y0 = (int)y0f, x0 = (int)x0f;
        int yc0 = min(max(y0, 0), HH - 1),     yc1 = min(max(y0 + 1, 0), HH - 1);
        int xc0 = min(max(x0, 0), WW - 1),     xc1 = min(max(x0 + 1, 0), WW - 1);
        float vy0 = (y0 >= 0 && y0 < HH) ? 1.f : 0.f;
        float vy1 = (y0 + 1 >= 0 && y0 + 1 < HH) ? 1.f : 0.f;
        float vx0 = (x0 >= 0 && x0 < WW) ? 1.f : 0.f;
        float vx1 = (x0 + 1 >= 0 && x0 + 1 < WW) ? 1.f : 0.f;
        sO[k][p] = (int4){(yc0 * WW + xc0) * 512, (yc0 * WW + xc1) * 512,
                          (yc1 * WW + xc0) * 512, (yc1 * WW + xc1) * 512};
        sW[k][p] = (float4){(1.f - ly) * (1.f - lx) * vy0 * vx0 * mm,
                            (1.f - ly) * lx         * vy0 * vx1 * mm,
                            ly         * (1.f - lx) * vy1 * vx0 * mm,
                            ly         * lx         * vy1 * vx1 * mm};
    }
    __syncthreads();

    // ---------------- Main: barrier-free K-split GEMM (r10) ---------------
    f32x4 acc[16];                       // 64 VGPRs
    #pragma unroll
    for (int j = 0; j < 16; j++) acc[j] = (f32x4){0.f, 0.f, 0.f, 0.f};

    for (int i = 0; i < 9; i++) {
        const int kb = wv * 9 + i;
        const int k = kb >> 2, cc = kb & 3;
        const int4   O = sO[k][n15];
        const float4 W = sW[k][n15];
        const char* base = xb + (cc * 64 + q4 * 8) * 2;

        bf16x8 af[2];
        #pragma unroll
        for (int ks = 0; ks < 2; ks++) {
            const char* bc = base + ks * 64;
            bf16x8 c00 = *(const bf16x8*)(bc + O.x);
            bf16x8 c01 = *(const bf16x8*)(bc + O.y);
            bf16x8 c10 = *(const bf16x8*)(bc + O.z);
            bf16x8 c11 = *(const bf16x8*)(bc + O.w);
            bf16x8 a;
            #pragma unroll
            for (int j = 0; j < 8; j++) {
                float v = W.x * (float)c00[j] + W.y * (float)c01[j]
                        + W.z * (float)c10[j] + W.w * (float)c11[j];
                a[j] = (__bf16)v;
            }
            af[ks] = a;
        }

        #pragma unroll
        for (int half = 0; half < 2; half++) {
            bf16x8 bfr[8][2];
            #pragma unroll
            for (int nb = 0; nb < 8; nb++)
                #pragma unroll
                for (int ks = 0; ks < 2; ks++)
                    bfr[nb][ks] = *(const bf16x8*)(wbfS
                        + ((size_t)(((kb * 2 + ks) * 16 + half * 8 + nb) * 64 + lane)) * 8);
            #pragma unroll
            for (int nb = 0; nb < 8; nb++)
                #pragma unroll
                for (int ks = 0; ks < 2; ks++)
                    acc[half * 8 + nb] = __builtin_amdgcn_mfma_f32_16x16x32_bf16(
                        af[ks], bfr[nb][ks], acc[half * 8 + nb], 0, 0, 0);
        }
    }

    // ---------------- 2-stage cross-wave K-reduction ----------------------
    if (wv < 2) {
        #pragma unroll
        for (int nb = 0; nb < 16; nb++)
            #pragma unroll
            for (int r = 0; r < 4; r++)
                u.sC[wv][q4 * 4 + r][nb * 16 + n15] = acc[nb][r];
    }
    __syncthreads();
    if (wv >= 2) {
        #pragma unroll
        for (int nb = 0; nb < 16; nb++)
            #pragma unroll
            for (int r = 0; r < 4; r++)
                u.sC[wv - 2][q4 * 4 + r][nb * 16 + n15] += acc[nb][r];
    }
    __syncthreads();

    // ---------------- Epilogue: BN + SiLU ---------------------------------
    const int px = tid & 15, og = tid >> 4;
    float* ob = out + ((size_t)b * C2 << 12) + hwBase + px;
    #pragma unroll
    for (int ii = 0; ii < 16; ii++) {
        int o = og * 16 + ii;
        float s = u.sC[0][px][o] + u.sC[1][px][o];
        float inv = gamma[o] * rsqrtf(rvar[o] + EPSV);
        float sh = beta[o] - rmean[o] * inv;
        float y = s * inv + sh;
        ob[(size_t)o << 12] = y * (1.f / (1.f + __expf(-y)));
    }
}

// ---------------------------------------------------------------------------
extern "C" void kernel_launch(void* const* d_in, const int* in_sizes, int n_in,
                              void* d_out, int out_size, void* d_ws, size_t ws_size,
                              hipStream_t stream) {
    const float* x      = (const float*)d_in[0];
    const float* w_off  = (const float*)d_in[1];
    const float* b_off  = (const float*)d_in[2];
    const float* w_dcn  = (const float*)d_in[3];
    const float* gamma  = (const float*)d_in[4];
    const float* beta   = (const float*)d_in[5];
    const float* rmean  = (const float*)d_in[6];
    const float* rvar   = (const float*)d_in[7];
    float* out = (float*)d_out;

    char* ws = (char*)d_ws;
    __bf16* wbfS  = (__bf16*)(ws + WBF_OFF);
    __bf16* woffS = (__bf16*)(ws + WOFF_OFF);
    __bf16* xT    = (__bf16*)(ws + XT_OFF);

    prep_kernel<<<612, 256, 0, stream>>>(x, w_dcn, w_off, xT, wbfS, woffS);
    fused_kernel<<<512, 256, 0, stream>>>(xT, wbfS, woffS, b_off,
                                          gamma, beta, rmean, rvar, out);
}